// Round 8
// baseline (428.540 us; speedup 1.0000x reference)
//
#include <hip/hip_runtime.h>

// Atom_embedding_MP: B=4, N=100000, K=16, D=6, C_IN=13, 3 layers.
// Round-10: FOUR threads per point -- the ZERO-SCRATCH configuration.
//  Unifying theory after 7 rounds: every variant hit ~10-11 resident
//  waves/CU via a different limiter, and the common cause is per-wave
//  backing stores:
//   R3/R8/R9: VGPR=60 can't hold a[48]+dq[8] -> arrays in SCRATCH ->
//     HW caps waves-in-flight to scratch backing (~2.5 blocks/CU);
//     persistent grid (R9) proved placement is capped: 24 waves/CU
//     demanded, ~10 resident.
//   R6: LDS version removed scratch but 48KB/block caps at 12 waves/CU.
//   R4/R5/R7: pins/budget -> allocator spilled anyway.
//  This round: 4 t/pt -> input state = a[24]+dq[4] = 28 floats; total
//  liveness ~70 -> compiles scratch-free, no LDS, VGPR ~90-100
//  -> static cap 20 waves/CU, double the observed ceiling.
//  Cost: tail duplicated x4 and 2-level shfl (+20% instrs, floor ~42us)
//  -- a good trade if residency doubles.
//  - d->j->k loop order (proven best, R3): W1 weights batched s_loads.
//  - lrelu-acc: sum += .6x + .4|x| (free |x| modifier).
//  - hsum[13] quad-reduced with __shfl_xor 1,2; tail redundant in quad.

constexpr int DD  = 6;
constexpr int KK  = 16;
constexpr int CIN = 13;
constexpr int TPB = 256;
constexpr float EPSV = 1e-5f;

__global__ __launch_bounds__(TPB) void atom_mp(
    const float* __restrict__ dist,   // [P, K]
    const float* __restrict__ at,     // [P, K, D]
    const float* __restrict__ W1,     // [3, CIN, CIN]
    const float* __restrict__ b1,     // [3, CIN]
    const float* __restrict__ W2,     // [3, CIN, D]
    const float* __restrict__ b2,     // [3, D]
    const float* __restrict__ gw,     // [3, D]
    const float* __restrict__ gb,     // [3, D]
    float* __restrict__ out,          // [P, D]
    int P)
{
    const int t = blockIdx.x * TPB + threadIdx.x;
    const int p = t >> 2;     // point index
    const int h = t & 3;      // quarter of the neighbors (4 each)
    if (p >= P) return;

    // ---- register-resident input: 4 neighbors x 6 feats + 4 dists --------
    float a[4 * DD];   // 24 floats
    float dq[4];

    const float4* ap4 = reinterpret_cast<const float4*>(
        at + (long)p * (KK * DD) + h * (4 * DD));
    #pragma unroll
    for (int i = 0; i < 6; ++i) {
        float4 q = ap4[i];
        a[4 * i + 0] = q.x; a[4 * i + 1] = q.y;
        a[4 * i + 2] = q.z; a[4 * i + 3] = q.w;
    }
    {
        float4 q = *reinterpret_cast<const float4*>(
            dist + (long)p * KK + h * 4);
        dq[0] = q.x; dq[1] = q.y; dq[2] = q.z; dq[3] = q.w;
    }

    float pe[DD] = {1.f, 1.f, 1.f, 1.f, 1.f, 1.f};

    #pragma unroll 1   // keep body in I$
    for (int L = 0; L < 3; ++L) {
        const float* w1  = W1 + L * CIN * CIN;
        const float* w2  = W2 + L * CIN * DD;
        const float* bb1 = b1 + L * CIN;
        const float* bb2 = b2 + L * DD;
        const float* gwp = gw + L * DD;
        const float* gbp = gb + L * DD;

        float hsum[CIN];

        #pragma unroll
        for (int d = 0; d < CIN; ++d) {
            // base_d = b1[d] + pe @ W1[0:6, d]
            float s = bb1[d];
            #pragma unroll
            for (int c = 0; c < DD; ++c)
                s = fmaf(pe[c], w1[c * CIN + d], s);

            // acc[k] over 4 neighbors; init folded into the j=0 FMA
            float w0 = w1[6 * CIN + d];
            float acc[4];
            #pragma unroll
            for (int k = 0; k < 4; ++k)
                acc[k] = fmaf(a[6 * k + 0], w0, s);
            #pragma unroll
            for (int j = 1; j < 7; ++j) {
                float w = w1[(6 + j) * CIN + d];
                #pragma unroll
                for (int k = 0; k < 4; ++k) {
                    float fv = (j < 6) ? a[6 * k + j] : dq[k];
                    acc[k] = fmaf(fv, w, acc[k]);
                }
            }
            // sum_k lrelu(acc[k]) = sum_k 0.6*acc + 0.4*|acc|
            float hs = 0.f;
            #pragma unroll
            for (int k = 0; k < 4; ++k) {
                hs = fmaf(0.6f, acc[k], hs);
                hs = fmaf(0.4f, __builtin_fabsf(acc[k]), hs);
            }
            hsum[d] = hs;
        }

        // reduce across the quad (lanes 4i..4i+3 hold quarters of point i)
        #pragma unroll
        for (int d = 0; d < CIN; ++d) {
            hsum[d] += __shfl_xor(hsum[d], 1, 64);
            hsum[d] += __shfl_xor(hsum[d], 2, 64);
        }

        // msg = hsum @ W2 + 16*b2   (all 4 lanes, redundantly)
        float msg[DD];
        #pragma unroll
        for (int d = 0; d < DD; ++d) {
            float m = 16.f * bb2[d];
            #pragma unroll
            for (int c = 0; c < CIN; ++c)
                m = fmaf(hsum[c], w2[c * DD + d], m);
            msg[d] = m;
        }

        // GroupNorm(2 groups of 3) + affine + lrelu, residual add
        #pragma unroll
        for (int g = 0; g < 2; ++g) {
            float m0 = msg[3 * g], m1 = msg[3 * g + 1], m2 = msg[3 * g + 2];
            float mu = (m0 + m1 + m2) * (1.f / 3.f);
            float d0 = m0 - mu, d1 = m1 - mu, d2 = m2 - mu;
            float var = (d0 * d0 + d1 * d1 + d2 * d2) * (1.f / 3.f);
            float rs = rsqrtf(var + EPSV);
            float dv[3] = {d0, d1, d2};
            #pragma unroll
            for (int c = 0; c < 3; ++c) {
                int ch = 3 * g + c;
                float xn = fmaf(dv[c] * rs, gwp[ch], gbp[ch]);
                pe[ch] = fmaf(0.6f, xn, pe[ch]);
                pe[ch] = fmaf(0.4f, __builtin_fabsf(xn), pe[ch]);
            }
        }
    }

    // all 4 lanes hold identical pe; lanes 0..2 store a float2 each
    float* op = out + (long)p * DD;
    if (h < 3)
        *reinterpret_cast<float2*>(op + 2 * h) =
            make_float2(pe[2 * h], pe[2 * h + 1]);
}

extern "C" void kernel_launch(void* const* d_in, const int* in_sizes, int n_in,
                              void* d_out, int out_size, void* d_ws, size_t ws_size,
                              hipStream_t stream) {
    const float* dist = (const float*)d_in[0];
    const float* at   = (const float*)d_in[1];
    const float* W1   = (const float*)d_in[2];
    const float* b1   = (const float*)d_in[3];
    const float* W2   = (const float*)d_in[4];
    const float* b2   = (const float*)d_in[5];
    const float* gw   = (const float*)d_in[6];
    const float* gb   = (const float*)d_in[7];
    float* out = (float*)d_out;

    int P = in_sizes[0] / KK;   // dist is [P, K]
    long threads_total = 4L * P;
    int blocks = (int)((threads_total + TPB - 1) / TPB);
    atom_mp<<<blocks, TPB, 0, stream>>>(dist, at, W1, b1, W2, b2, gw, gb, out, P);
}

// Round 9
// 269.261 us; speedup vs baseline: 1.5915x; 1.5915x over previous
//
#include <hip/hip_runtime.h>

// Atom_embedding_MP: B=4, N=100000, K=16, D=6, C_IN=13, 3 layers.
// Round-11: ZERO-SCRATCH / ZERO-LDS / low-VGPR global-stream k-pair-outer.
//  Model after 8 rounds:
//   - R3 baseline (102.7us): VGPR=60 -> a[48]+dq[8] in SCRATCH -> waves
//     capped ~11/CU by scratch backing; each wave stalls ~85% of life on
//     serialized per-layer input reloads (only ~20 spare VGPRs -> 10
//     load/wait chunks per layer at L3 latency).
//   - R10 (4t/pt): arrays PromoteAlloca'd to LDS (6KB, 24B/thread slices)
//     -> 4-way bank conflicts on every access (SQ_LDS_BANK_CONFLICT=1M)
//     -> 400us. BUT occupancy rose 36->49%: scratch-cap confirmed.
//   - R6 (LDS staging): no scratch but 48KB LDS caps 12 waves/CU -> 111us.
//  This round: k-pair-outer body (per-pair liveness = 12 in-flight floats
//  + hs1/hs2/base/x accumulators ~ 82 VGPR), inputs re-streamed from
//  global each layer (re-read traffic proven non-binding by R6).
//  Nothing for PromoteAlloca, no LDS, no scratch -> ~6 waves/SIMD static.
//  All 12 float4 loads/layer can issue ahead of one wait (vs R3's
//  serialized chunks).
//  - row-contiguous weight access (c-outer/d-inner) -> batched s_loads.
//  - lrelu linearity: Sum_k lrelu(x) = .6*Sum x + .4*Sum |x|.
//  - hsum[13] pair-reduced via __shfl_xor(.,1); tail redundant in pair.

constexpr int DD  = 6;
constexpr int KK  = 16;
constexpr int CIN = 13;
constexpr int TPB = 256;
constexpr float EPSV = 1e-5f;

__global__ __launch_bounds__(TPB) void atom_mp(
    const float* __restrict__ dist,   // [P, K]
    const float* __restrict__ at,     // [P, K, D]
    const float* __restrict__ W1,     // [3, CIN, CIN]
    const float* __restrict__ b1,     // [3, CIN]
    const float* __restrict__ W2,     // [3, CIN, D]
    const float* __restrict__ b2,     // [3, D]
    const float* __restrict__ gw,     // [3, D]
    const float* __restrict__ gb,     // [3, D]
    float* __restrict__ out,          // [P, D]
    int P)
{
    const int t = blockIdx.x * TPB + threadIdx.x;
    const int p = t >> 1;      // point index
    const int h = t & 1;       // which half of the neighbors (8 each)
    if (p >= P) return;

    // this thread's 8 neighbors: 48 floats, 16B-aligned (h*192B offset)
    const float* __restrict__ ab = at + (long)p * (KK * DD) + h * (8 * DD);

    // distances: 8 floats, kept in registers all 3 layers (small, safe)
    float dq[8];
    {
        const float4* dp4 = reinterpret_cast<const float4*>(
            dist + (long)p * KK + h * 8);
        float4 q0 = dp4[0], q1 = dp4[1];
        dq[0] = q0.x; dq[1] = q0.y; dq[2] = q0.z; dq[3] = q0.w;
        dq[4] = q1.x; dq[5] = q1.y; dq[6] = q1.z; dq[7] = q1.w;
    }

    float pe[DD] = {1.f, 1.f, 1.f, 1.f, 1.f, 1.f};

    #pragma unroll 1   // keep body in I$
    for (int L = 0; L < 3; ++L) {
        const float* w1  = W1 + L * CIN * CIN;
        const float* w2  = W2 + L * CIN * DD;
        const float* bb1 = b1 + L * CIN;
        const float* bb2 = b2 + L * DD;
        const float* gwp = gw + L * DD;
        const float* gbp = gb + L * DD;

        // base[d] = b1[d] + pe @ W1[0:6, d]  (row-contiguous weight reads)
        float base[CIN];
        #pragma unroll
        for (int d = 0; d < CIN; ++d) base[d] = bb1[d];
        #pragma unroll
        for (int c = 0; c < DD; ++c) {
            const float pc = pe[c];
            const float* wr = w1 + c * CIN;
            #pragma unroll
            for (int d = 0; d < CIN; ++d)
                base[d] = fmaf(pc, wr[d], base[d]);
        }

        float hs1[CIN], hs2[CIN];
        #pragma unroll
        for (int d = 0; d < CIN; ++d) { hs1[d] = 0.f; hs2[d] = 0.f; }

        // 4 neighbor-PAIRS: 12 floats = 3 aligned float4 per pair.
        // Within a pair the two neighbors share one x[] (sequential) to
        // keep liveness low; across pairs the loads pipeline freely.
        #pragma unroll
        for (int kp = 0; kp < 4; ++kp) {
            const float4* fp4 = reinterpret_cast<const float4*>(ab + kp * 12);
            const float4 A = fp4[0];
            const float4 B = fp4[1];
            const float4 C = fp4[2];

            // ---- neighbor 2*kp: feats A.x A.y A.z A.w B.x B.y ----------
            {
                const float f0 = A.x, f1 = A.y, f2 = A.z,
                            f3 = A.w, f4 = B.x, f5 = B.y;
                const float fd = dq[2 * kp];
                float x[CIN];
                #pragma unroll
                for (int d = 0; d < CIN; ++d) x[d] = base[d];
                const float* wr6  = w1 +  6 * CIN;
                const float* wr7  = w1 +  7 * CIN;
                const float* wr8  = w1 +  8 * CIN;
                const float* wr9  = w1 +  9 * CIN;
                const float* wr10 = w1 + 10 * CIN;
                const float* wr11 = w1 + 11 * CIN;
                const float* wr12 = w1 + 12 * CIN;
                #pragma unroll
                for (int d = 0; d < CIN; ++d) {
                    float xx = x[d];
                    xx = fmaf(f0, wr6[d],  xx);
                    xx = fmaf(f1, wr7[d],  xx);
                    xx = fmaf(f2, wr8[d],  xx);
                    xx = fmaf(f3, wr9[d],  xx);
                    xx = fmaf(f4, wr10[d], xx);
                    xx = fmaf(f5, wr11[d], xx);
                    xx = fmaf(fd, wr12[d], xx);
                    hs1[d] += xx;
                    hs2[d] += __builtin_fabsf(xx);
                }
            }
            // ---- neighbor 2*kp+1: feats B.z B.w C.x C.y C.z C.w --------
            {
                const float f0 = B.z, f1 = B.w, f2 = C.x,
                            f3 = C.y, f4 = C.z, f5 = C.w;
                const float fd = dq[2 * kp + 1];
                const float* wr6  = w1 +  6 * CIN;
                const float* wr7  = w1 +  7 * CIN;
                const float* wr8  = w1 +  8 * CIN;
                const float* wr9  = w1 +  9 * CIN;
                const float* wr10 = w1 + 10 * CIN;
                const float* wr11 = w1 + 11 * CIN;
                const float* wr12 = w1 + 12 * CIN;
                #pragma unroll
                for (int d = 0; d < CIN; ++d) {
                    float xx = base[d];
                    xx = fmaf(f0, wr6[d],  xx);
                    xx = fmaf(f1, wr7[d],  xx);
                    xx = fmaf(f2, wr8[d],  xx);
                    xx = fmaf(f3, wr9[d],  xx);
                    xx = fmaf(f4, wr10[d], xx);
                    xx = fmaf(f5, wr11[d], xx);
                    xx = fmaf(fd, wr12[d], xx);
                    hs1[d] += xx;
                    hs2[d] += __builtin_fabsf(xx);
                }
            }
        }

        // lrelu-after-sum + pair reduction (lanes 2i, 2i+1 share point i)
        float hsum[CIN];
        #pragma unroll
        for (int d = 0; d < CIN; ++d)
            hsum[d] = fmaf(0.6f, hs1[d], 0.4f * hs2[d]);
        #pragma unroll
        for (int d = 0; d < CIN; ++d)
            hsum[d] += __shfl_xor(hsum[d], 1, 64);

        // msg = hsum @ W2 + 16*b2   (row-contiguous; both lanes redundant)
        float msg[DD];
        #pragma unroll
        for (int d = 0; d < DD; ++d) msg[d] = 16.f * bb2[d];
        #pragma unroll
        for (int c = 0; c < CIN; ++c) {
            const float hc = hsum[c];
            const float* wr = w2 + c * DD;
            #pragma unroll
            for (int d = 0; d < DD; ++d)
                msg[d] = fmaf(hc, wr[d], msg[d]);
        }

        // GroupNorm(2 groups of 3) + affine + lrelu, residual add
        #pragma unroll
        for (int g = 0; g < 2; ++g) {
            float m0 = msg[3 * g], m1 = msg[3 * g + 1], m2 = msg[3 * g + 2];
            float mu = (m0 + m1 + m2) * (1.f / 3.f);
            float d0 = m0 - mu, d1 = m1 - mu, d2 = m2 - mu;
            float var = (d0 * d0 + d1 * d1 + d2 * d2) * (1.f / 3.f);
            float rs = rsqrtf(var + EPSV);
            float dv[3] = {d0, d1, d2};
            #pragma unroll
            for (int c = 0; c < 3; ++c) {
                int ch = 3 * g + c;
                float xn = fmaf(dv[c] * rs, gwp[ch], gbp[ch]);
                pe[ch] = fmaf(0.6f, xn, pe[ch]);
                pe[ch] = fmaf(0.4f, __builtin_fabsf(xn), pe[ch]);
            }
        }
    }

    // both lanes hold identical pe; split the 6-float store across the pair
    float* op = out + (long)p * DD;
    if (h == 0) {
        *reinterpret_cast<float2*>(op)     = make_float2(pe[0], pe[1]);
        *reinterpret_cast<float2*>(op + 2) = make_float2(pe[2], pe[3]);
    } else {
        *reinterpret_cast<float2*>(op + 4) = make_float2(pe[4], pe[5]);
    }
}

extern "C" void kernel_launch(void* const* d_in, const int* in_sizes, int n_in,
                              void* d_out, int out_size, void* d_ws, size_t ws_size,
                              hipStream_t stream) {
    const float* dist = (const float*)d_in[0];
    const float* at   = (const float*)d_in[1];
    const float* W1   = (const float*)d_in[2];
    const float* b1   = (const float*)d_in[3];
    const float* W2   = (const float*)d_in[4];
    const float* b2   = (const float*)d_in[5];
    const float* gw   = (const float*)d_in[6];
    const float* gb   = (const float*)d_in[7];
    float* out = (float*)d_out;

    int P = in_sizes[0] / KK;   // dist is [P, K]
    long threads_total = 2L * P;
    int blocks = (int)((threads_total + TPB - 1) / TPB);
    atom_mp<<<blocks, TPB, 0, stream>>>(dist, at, W1, b1, W2, b2, gw, gb, out, P);
}